// Round 1
// baseline (1223.873 us; speedup 1.0000x reference)
//
#include <hip/hip_runtime.h>

#define N_NODES 50000
#define N_EDGES 800000
#define D 128
#define HEADS 8

// ---------------- K1: hs = nodes@Ws + bs ; hr = nodes@Wr + br ----------------
// One block per (projection, 32-node tile). W (64KB) + node tile (16KB) in LDS.
__global__ __launch_bounds__(256) void k_node_proj(
    const float* __restrict__ nodes,
    const float* __restrict__ Ws, const float* __restrict__ bs,
    const float* __restrict__ Wr, const float* __restrict__ br,
    float* __restrict__ hs, float* __restrict__ hr)
{
    __shared__ float Wl[D][D];    // 64 KB
    __shared__ float Al[32][D];   // 16 KB
    const int ntiles = (N_NODES + 31) / 32;
    int bx = blockIdx.x;
    int proj = (bx >= ntiles) ? 1 : 0;
    int tile = proj ? (bx - ntiles) : bx;
    const float* W    = proj ? Wr : Ws;
    const float* bias = proj ? br : bs;
    float* outp       = proj ? hr : hs;
    int t = threadIdx.x;

    {   // load W -> LDS (16384 floats = 4096 float4)
        const float4* Wv = (const float4*)W;
        float4* Wlv = (float4*)&Wl[0][0];
        #pragma unroll
        for (int j = 0; j < 16; ++j) Wlv[t + 256 * j] = Wv[t + 256 * j];
    }
    int row0 = tile * 32;
    {   // stage 32 node rows (guarded)
        const float4* Nv = (const float4*)nodes;
        float4* Alv = (float4*)&Al[0][0];
        #pragma unroll
        for (int j = 0; j < 4; ++j) {
            int idx = t + 256 * j;            // float4 slot 0..1023
            int r = row0 + (idx >> 5);
            float4 v = make_float4(0.f, 0.f, 0.f, 0.f);
            if (r < N_NODES) v = Nv[(size_t)r * 32 + (idx & 31)];
            Alv[idx] = v;
        }
    }
    __syncthreads();

    int c = t & 31;   // col group: cols 4c..4c+3
    int g = t >> 5;   // row group: rows 4g..4g+3
    float acc[4][4];
    #pragma unroll
    for (int i = 0; i < 4; ++i)
        #pragma unroll
        for (int j = 0; j < 4; ++j) acc[i][j] = 0.f;

    #pragma unroll 4
    for (int k = 0; k < D; ++k) {
        float4 b4 = *(const float4*)&Wl[k][4 * c];
        #pragma unroll
        for (int i = 0; i < 4; ++i) {
            float av = Al[4 * g + i][k];
            acc[i][0] += av * b4.x; acc[i][1] += av * b4.y;
            acc[i][2] += av * b4.z; acc[i][3] += av * b4.w;
        }
    }
    float4 bv = *(const float4*)&bias[4 * c];
    #pragma unroll
    for (int i = 0; i < 4; ++i) {
        int r = row0 + 4 * g + i;
        if (r < N_NODES) {
            float4 o;
            o.x = acc[i][0] + bv.x; o.y = acc[i][1] + bv.y;
            o.z = acc[i][2] + bv.z; o.w = acc[i][3] + bv.w;
            *(float4*)&outp[(size_t)r * D + 4 * c] = o;
        }
    }
}

// ------- K2: per-edge he GEMM + leaky + per-head logit -> ex, denom ---------
__global__ __launch_bounds__(256) void k_edge_logits(
    const float* __restrict__ edges,
    const int* __restrict__ senders, const int* __restrict__ receivers,
    const float* __restrict__ We, const float* __restrict__ be,
    const float* __restrict__ a,
    const float* __restrict__ hs, const float* __restrict__ hr,
    float* __restrict__ ex, float* __restrict__ denom)
{
    __shared__ float Wl[D][D];    // 64 KB
    __shared__ float El[32][D];   // 16 KB
    int t = threadIdx.x;
    {
        const float4* Wv = (const float4*)We;
        float4* Wlv = (float4*)&Wl[0][0];
        #pragma unroll
        for (int j = 0; j < 16; ++j) Wlv[t + 256 * j] = Wv[t + 256 * j];
    }
    int c = t & 31;   // cols 4c..4c+3  (head h = c>>2, a-flat index == col)
    int g = t >> 5;   // edges 4g..4g+3 within tile
    float4 av  = *(const float4*)&a[4 * c];
    float4 bev = *(const float4*)&be[4 * c];

    const int ntiles = N_EDGES / 32;   // 25000, exact
    for (int tile = blockIdx.x; tile < ntiles; tile += gridDim.x) {
        __syncthreads();   // W ready (iter 0) / previous El reads done
        {   // stage 32 edge rows -> LDS
            const float4* Ev = (const float4*)edges;
            float4* Elv = (float4*)&El[0][0];
            size_t base = (size_t)tile * 1024;   // 32 rows * 32 float4
            #pragma unroll
            for (int j = 0; j < 4; ++j) Elv[t + 256 * j] = Ev[base + t + 256 * j];
        }
        __syncthreads();

        float acc[4][4];
        #pragma unroll
        for (int i = 0; i < 4; ++i)
            #pragma unroll
            for (int j = 0; j < 4; ++j) acc[i][j] = 0.f;

        #pragma unroll 4
        for (int k = 0; k < D; ++k) {
            float4 b4 = *(const float4*)&Wl[k][4 * c];
            #pragma unroll
            for (int i = 0; i < 4; ++i) {
                float av2 = El[4 * g + i][k];
                acc[i][0] += av2 * b4.x; acc[i][1] += av2 * b4.y;
                acc[i][2] += av2 * b4.z; acc[i][3] += av2 * b4.w;
            }
        }

        #pragma unroll
        for (int i = 0; i < 4; ++i) {
            int eid = tile * 32 + 4 * g + i;
            int s = senders[eid];
            int r = receivers[eid];
            float4 hsv = *(const float4*)&hs[(size_t)s * D + 4 * c];
            float4 hrv = *(const float4*)&hr[(size_t)r * D + 4 * c];
            float p = 0.f, xj;
            xj = acc[i][0] + bev.x + hsv.x + hrv.x; xj = xj > 0.f ? xj : 0.01f * xj; p += xj * av.x;
            xj = acc[i][1] + bev.y + hsv.y + hrv.y; xj = xj > 0.f ? xj : 0.01f * xj; p += xj * av.y;
            xj = acc[i][2] + bev.z + hsv.z + hrv.z; xj = xj > 0.f ? xj : 0.01f * xj; p += xj * av.z;
            xj = acc[i][3] + bev.w + hsv.w + hrv.w; xj = xj > 0.f ? xj : 0.01f * xj; p += xj * av.w;
            // reduce over the 4 lanes of one head
            p += __shfl_xor(p, 1);
            p += __shfl_xor(p, 2);
            float e_ = expf(p);    // no max-subtraction: w = ex/denom invariant
            if ((c & 3) == 0) {
                int h = c >> 2;
                ex[(size_t)eid * HEADS + h] = e_;
                atomicAdd(&denom[(size_t)r * HEADS + h], e_);
            }
        }
    }
}

// ---------- K3: out[r] += (ex/denom[r]) * hs[s]  (atomic scatter) -----------
__global__ __launch_bounds__(256) void k_scatter_out(
    const int* __restrict__ senders, const int* __restrict__ receivers,
    const float* __restrict__ hs, const float* __restrict__ ex,
    const float* __restrict__ denom, float* __restrict__ out)
{
    int t = threadIdx.x;
    int lane = t & 63;            // cols 2*lane, 2*lane+1
    int esub = t >> 6;            // 0..3
    int h = lane >> 3;            // head for these cols
    for (int e0 = blockIdx.x * 4; e0 < N_EDGES; e0 += gridDim.x * 4) {
        int eid = e0 + esub;      // N_EDGES % 4 == 0
        int s = senders[eid];
        int r = receivers[eid];
        float exv = ex[(size_t)eid * HEADS + h];
        float den = denom[(size_t)r * HEADS + h];
        float w = exv / den;
        float2 hv = *(const float2*)&hs[(size_t)s * D + 2 * lane];
        atomicAdd(&out[(size_t)r * D + 2 * lane],     w * hv.x);
        atomicAdd(&out[(size_t)r * D + 2 * lane + 1], w * hv.y);
    }
}

extern "C" void kernel_launch(void* const* d_in, const int* in_sizes, int n_in,
                              void* d_out, int out_size, void* d_ws, size_t ws_size,
                              hipStream_t stream) {
    const float* nodes     = (const float*)d_in[0];
    const float* edges     = (const float*)d_in[1];
    const int*   senders   = (const int*)d_in[2];
    const int*   receivers = (const int*)d_in[3];
    const float* Ws = (const float*)d_in[4];
    const float* bs = (const float*)d_in[5];
    const float* Wr = (const float*)d_in[6];
    const float* br = (const float*)d_in[7];
    const float* We = (const float*)d_in[8];
    const float* be = (const float*)d_in[9];
    const float* a  = (const float*)d_in[10];
    float* out = (float*)d_out;

    float* hs    = (float*)d_ws;                       // 6.4M f32
    float* hr    = hs + (size_t)N_NODES * D;           // 6.4M f32
    float* ex    = hr + (size_t)N_NODES * D;           // 6.4M f32
    float* denom = ex + (size_t)N_EDGES * HEADS;       // 0.4M f32

    hipMemsetAsync(out,   0, (size_t)N_NODES * D * sizeof(float), stream);
    hipMemsetAsync(denom, 0, (size_t)N_NODES * HEADS * sizeof(float), stream);

    int ntiles_n = (N_NODES + 31) / 32;
    k_node_proj<<<ntiles_n * 2, 256, 0, stream>>>(nodes, Ws, bs, Wr, br, hs, hr);
    k_edge_logits<<<2048, 256, 0, stream>>>(edges, senders, receivers, We, be, a,
                                            hs, hr, ex, denom);
    k_scatter_out<<<4096, 256, 0, stream>>>(senders, receivers, hs, ex, denom, out);
}

// Round 2
// 888.043 us; speedup vs baseline: 1.3782x; 1.3782x over previous
//
#include <hip/hip_runtime.h>

#define N_NODES 50000
#define N_EDGES 800000
#define D 128
#define HEADS 8

// ---------------- K1: hs = nodes@Ws + bs ; hr = nodes@Wr + br ----------------
__global__ __launch_bounds__(256) void k_node_proj(
    const float* __restrict__ nodes,
    const float* __restrict__ Ws, const float* __restrict__ bs,
    const float* __restrict__ Wr, const float* __restrict__ br,
    float* __restrict__ hs, float* __restrict__ hr)
{
    __shared__ float Wl[D][D];    // 64 KB
    __shared__ float Al[32][D];   // 16 KB
    const int ntiles = (N_NODES + 31) / 32;
    int bx = blockIdx.x;
    int proj = (bx >= ntiles) ? 1 : 0;
    int tile = proj ? (bx - ntiles) : bx;
    const float* W    = proj ? Wr : Ws;
    const float* bias = proj ? br : bs;
    float* outp       = proj ? hr : hs;
    int t = threadIdx.x;

    {   // load W -> LDS
        const float4* Wv = (const float4*)W;
        float4* Wlv = (float4*)&Wl[0][0];
        #pragma unroll
        for (int j = 0; j < 16; ++j) Wlv[t + 256 * j] = Wv[t + 256 * j];
    }
    int row0 = tile * 32;
    {   // stage 32 node rows (guarded)
        const float4* Nv = (const float4*)nodes;
        float4* Alv = (float4*)&Al[0][0];
        #pragma unroll
        for (int j = 0; j < 4; ++j) {
            int idx = t + 256 * j;
            int r = row0 + (idx >> 5);
            float4 v = make_float4(0.f, 0.f, 0.f, 0.f);
            if (r < N_NODES) v = Nv[(size_t)r * 32 + (idx & 31)];
            Alv[idx] = v;
        }
    }
    __syncthreads();

    int c = t & 31;
    int g = t >> 5;
    float acc[4][4];
    #pragma unroll
    for (int i = 0; i < 4; ++i)
        #pragma unroll
        for (int j = 0; j < 4; ++j) acc[i][j] = 0.f;

    #pragma unroll 4
    for (int k = 0; k < D; ++k) {
        float4 b4 = *(const float4*)&Wl[k][4 * c];
        #pragma unroll
        for (int i = 0; i < 4; ++i) {
            float av = Al[4 * g + i][k];
            acc[i][0] += av * b4.x; acc[i][1] += av * b4.y;
            acc[i][2] += av * b4.z; acc[i][3] += av * b4.w;
        }
    }
    float4 bv = *(const float4*)&bias[4 * c];
    #pragma unroll
    for (int i = 0; i < 4; ++i) {
        int r = row0 + 4 * g + i;
        if (r < N_NODES) {
            float4 o;
            o.x = acc[i][0] + bv.x; o.y = acc[i][1] + bv.y;
            o.z = acc[i][2] + bv.z; o.w = acc[i][3] + bv.w;
            *(float4*)&outp[(size_t)r * D + 4 * c] = o;
        }
    }
}

// ------- K2: per-edge he GEMM + leaky + per-head logit -> ex (no atomics) ----
__global__ __launch_bounds__(256) void k_edge_logits(
    const float* __restrict__ edges,
    const int* __restrict__ senders, const int* __restrict__ receivers,
    const float* __restrict__ We, const float* __restrict__ be,
    const float* __restrict__ a,
    const float* __restrict__ hs, const float* __restrict__ hr,
    float* __restrict__ ex)
{
    __shared__ float Wl[D][D];    // 64 KB
    __shared__ float El[32][D];   // 16 KB
    int t = threadIdx.x;
    {
        const float4* Wv = (const float4*)We;
        float4* Wlv = (float4*)&Wl[0][0];
        #pragma unroll
        for (int j = 0; j < 16; ++j) Wlv[t + 256 * j] = Wv[t + 256 * j];
    }
    int c = t & 31;   // cols 4c..4c+3  (head h = c>>2)
    int g = t >> 5;   // edges 4g..4g+3 within tile
    float4 av  = *(const float4*)&a[4 * c];
    float4 bev = *(const float4*)&be[4 * c];

    const int ntiles = N_EDGES / 32;   // 25000, exact
    for (int tile = blockIdx.x; tile < ntiles; tile += gridDim.x) {
        __syncthreads();
        {   // stage 32 edge rows -> LDS
            const float4* Ev = (const float4*)edges;
            float4* Elv = (float4*)&El[0][0];
            size_t base = (size_t)tile * 1024;
            #pragma unroll
            for (int j = 0; j < 4; ++j) Elv[t + 256 * j] = Ev[base + t + 256 * j];
        }
        __syncthreads();

        float acc[4][4];
        #pragma unroll
        for (int i = 0; i < 4; ++i)
            #pragma unroll
            for (int j = 0; j < 4; ++j) acc[i][j] = 0.f;

        #pragma unroll 4
        for (int k = 0; k < D; ++k) {
            float4 b4 = *(const float4*)&Wl[k][4 * c];
            #pragma unroll
            for (int i = 0; i < 4; ++i) {
                float av2 = El[4 * g + i][k];
                acc[i][0] += av2 * b4.x; acc[i][1] += av2 * b4.y;
                acc[i][2] += av2 * b4.z; acc[i][3] += av2 * b4.w;
            }
        }

        #pragma unroll
        for (int i = 0; i < 4; ++i) {
            int eid = tile * 32 + 4 * g + i;
            int s = senders[eid];
            int r = receivers[eid];
            float4 hsv = *(const float4*)&hs[(size_t)s * D + 4 * c];
            float4 hrv = *(const float4*)&hr[(size_t)r * D + 4 * c];
            float p = 0.f, xj;
            xj = acc[i][0] + bev.x + hsv.x + hrv.x; xj = xj > 0.f ? xj : 0.01f * xj; p += xj * av.x;
            xj = acc[i][1] + bev.y + hsv.y + hrv.y; xj = xj > 0.f ? xj : 0.01f * xj; p += xj * av.y;
            xj = acc[i][2] + bev.z + hsv.z + hrv.z; xj = xj > 0.f ? xj : 0.01f * xj; p += xj * av.z;
            xj = acc[i][3] + bev.w + hsv.w + hrv.w; xj = xj > 0.f ? xj : 0.01f * xj; p += xj * av.w;
            p += __shfl_xor(p, 1);
            p += __shfl_xor(p, 2);
            if ((c & 3) == 0) {
                ex[(size_t)eid * HEADS + (c >> 2)] = expf(p);
            }
        }
    }
}

// ------------------------- CSR build (per call) ------------------------------
__global__ __launch_bounds__(256) void k_hist(
    const int* __restrict__ receivers, int* __restrict__ deg)
{
    int i = blockIdx.x * 256 + threadIdx.x;
    if (i < N_EDGES) atomicAdd(&deg[receivers[i]], 1);
}

#define SCAN_CHUNK 49   // ceil(50000/1024)
__global__ __launch_bounds__(1024) void k_scan(
    const int* __restrict__ deg, int* __restrict__ rowptr, int* __restrict__ cursor)
{
    __shared__ int sm[1024];
    int t = threadIdx.x;
    int base = t * SCAN_CHUNK;
    int lsum = 0;
    #pragma unroll 4
    for (int i = 0; i < SCAN_CHUNK; ++i) {
        int idx = base + i;
        if (idx < N_NODES) lsum += deg[idx];
    }
    sm[t] = lsum;
    __syncthreads();
    for (int off = 1; off < 1024; off <<= 1) {
        int v = (t >= off) ? sm[t - off] : 0;
        __syncthreads();
        sm[t] += v;
        __syncthreads();
    }
    int run = (t > 0) ? sm[t - 1] : 0;
    for (int i = 0; i < SCAN_CHUNK; ++i) {
        int idx = base + i;
        if (idx < N_NODES) {
            rowptr[idx] = run;
            cursor[idx] = run;
            run += deg[idx];
        }
    }
    if (t == 1023) rowptr[N_NODES] = sm[1023];
}

__global__ __launch_bounds__(256) void k_fill(
    const int* __restrict__ receivers, int* __restrict__ cursor,
    int* __restrict__ eids)
{
    int i = blockIdx.x * 256 + threadIdx.x;
    if (i < N_EDGES) {
        int r = receivers[i];
        int pos = atomicAdd(&cursor[r], 1);
        eids[pos] = i;
    }
}

// ---------- K3': per-node gather: denom + weighted sum, write once ----------
__global__ __launch_bounds__(256) void k_gather_out(
    const int* __restrict__ rowptr, const int* __restrict__ eids,
    const int* __restrict__ senders,
    const float* __restrict__ hs, const float* __restrict__ ex,
    float* __restrict__ out)
{
    int r = blockIdx.x * 4 + (threadIdx.x >> 6);   // wave per node; 50000 % 4 == 0
    int l = threadIdx.x & 63;                      // cols 2l, 2l+1
    int h = l >> 3;                                // head of these cols
    int beg = rowptr[r], end = rowptr[r + 1];

    // pass 1: per-head denom (lane-group parallel over edges)
    float dsum = 0.f;
    for (int j = beg + (l & 7); j < end; j += 8) {
        int e = eids[j];
        dsum += ex[(size_t)e * HEADS + h];
    }
    dsum += __shfl_xor(dsum, 1);
    dsum += __shfl_xor(dsum, 2);
    dsum += __shfl_xor(dsum, 4);
    float inv = 1.0f / dsum;   // only used when edges exist

    // pass 2: weighted accumulate
    float2 acc = make_float2(0.f, 0.f);
    for (int j = beg; j < end; ++j) {
        int e = eids[j];
        float w = ex[(size_t)e * HEADS + h] * inv;
        int s = senders[e];
        float2 hv = *(const float2*)&hs[(size_t)s * D + 2 * l];
        acc.x += w * hv.x;
        acc.y += w * hv.y;
    }
    *(float2*)&out[(size_t)r * D + 2 * l] = acc;
}

extern "C" void kernel_launch(void* const* d_in, const int* in_sizes, int n_in,
                              void* d_out, int out_size, void* d_ws, size_t ws_size,
                              hipStream_t stream) {
    const float* nodes     = (const float*)d_in[0];
    const float* edges     = (const float*)d_in[1];
    const int*   senders   = (const int*)d_in[2];
    const int*   receivers = (const int*)d_in[3];
    const float* Ws = (const float*)d_in[4];
    const float* bs = (const float*)d_in[5];
    const float* Wr = (const float*)d_in[6];
    const float* br = (const float*)d_in[7];
    const float* We = (const float*)d_in[8];
    const float* be = (const float*)d_in[9];
    const float* a  = (const float*)d_in[10];
    float* out = (float*)d_out;

    float* hs = (float*)d_ws;                         // 6.4M f32
    float* hr = hs + (size_t)N_NODES * D;             // 6.4M f32 (dead after K2)
    float* ex = hr + (size_t)N_NODES * D;             // 6.4M f32
    // CSR arrays reuse hr's region (hr not read after k_edge_logits)
    int* deg    = (int*)hr;                           // 50000
    int* rowptr = deg + N_NODES;                      // 50001
    int* cursor = rowptr + N_NODES + 1;               // 50000
    int* eids   = cursor + N_NODES;                   // 800000

    int ntiles_n = (N_NODES + 31) / 32;
    k_node_proj<<<ntiles_n * 2, 256, 0, stream>>>(nodes, Ws, bs, Wr, br, hs, hr);
    k_edge_logits<<<2048, 256, 0, stream>>>(edges, senders, receivers, We, be, a,
                                            hs, hr, ex);
    // CSR build (after K2: it overwrites hr's region)
    hipMemsetAsync(deg, 0, N_NODES * sizeof(int), stream);
    k_hist<<<N_EDGES / 256, 256, 0, stream>>>(receivers, deg);
    k_scan<<<1, 1024, 0, stream>>>(deg, rowptr, cursor);
    k_fill<<<N_EDGES / 256, 256, 0, stream>>>(receivers, cursor, eids);
    // gather
    k_gather_out<<<N_NODES / 4, 256, 0, stream>>>(rowptr, eids, senders, hs, ex, out);
}

// Round 3
// 685.526 us; speedup vs baseline: 1.7853x; 1.2954x over previous
//
#include <hip/hip_runtime.h>

#define N_NODES 50000
#define N_EDGES 800000
#define D 128
#define HEADS 8

typedef __attribute__((ext_vector_type(8))) short short8b;  // 8 bf16 (4 VGPRs)
typedef __attribute__((ext_vector_type(4))) float f32x4;

__device__ __forceinline__ unsigned short f2bf_rne(float f) {
    unsigned int u = __float_as_uint(f);
    u += 0x7FFFu + ((u >> 16) & 1u);   // round-to-nearest-even
    return (unsigned short)(u >> 16);
}

// ---------------- K1: hs = nodes@Ws + bs ; hr = nodes@Wr + br ----------------
__global__ __launch_bounds__(256) void k_node_proj(
    const float* __restrict__ nodes,
    const float* __restrict__ Ws, const float* __restrict__ bs,
    const float* __restrict__ Wr, const float* __restrict__ br,
    float* __restrict__ hs, float* __restrict__ hr)
{
    __shared__ float Wl[D][D];    // 64 KB
    __shared__ float Al[32][D];   // 16 KB
    const int ntiles = (N_NODES + 31) / 32;
    int bx = blockIdx.x;
    int proj = (bx >= ntiles) ? 1 : 0;
    int tile = proj ? (bx - ntiles) : bx;
    const float* W    = proj ? Wr : Ws;
    const float* bias = proj ? br : bs;
    float* outp       = proj ? hr : hs;
    int t = threadIdx.x;

    {
        const float4* Wv = (const float4*)W;
        float4* Wlv = (float4*)&Wl[0][0];
        #pragma unroll
        for (int j = 0; j < 16; ++j) Wlv[t + 256 * j] = Wv[t + 256 * j];
    }
    int row0 = tile * 32;
    {
        const float4* Nv = (const float4*)nodes;
        float4* Alv = (float4*)&Al[0][0];
        #pragma unroll
        for (int j = 0; j < 4; ++j) {
            int idx = t + 256 * j;
            int r = row0 + (idx >> 5);
            float4 v = make_float4(0.f, 0.f, 0.f, 0.f);
            if (r < N_NODES) v = Nv[(size_t)r * 32 + (idx & 31)];
            Alv[idx] = v;
        }
    }
    __syncthreads();

    int c = t & 31;
    int g = t >> 5;
    float acc[4][4];
    #pragma unroll
    for (int i = 0; i < 4; ++i)
        #pragma unroll
        for (int j = 0; j < 4; ++j) acc[i][j] = 0.f;

    #pragma unroll 4
    for (int k = 0; k < D; ++k) {
        float4 b4 = *(const float4*)&Wl[k][4 * c];
        #pragma unroll
        for (int i = 0; i < 4; ++i) {
            float av = Al[4 * g + i][k];
            acc[i][0] += av * b4.x; acc[i][1] += av * b4.y;
            acc[i][2] += av * b4.z; acc[i][3] += av * b4.w;
        }
    }
    float4 bv = *(const float4*)&bias[4 * c];
    #pragma unroll
    for (int i = 0; i < 4; ++i) {
        int r = row0 + 4 * g + i;
        if (r < N_NODES) {
            float4 o;
            o.x = acc[i][0] + bv.x; o.y = acc[i][1] + bv.y;
            o.z = acc[i][2] + bv.z; o.w = acc[i][3] + bv.w;
            *(float4*)&outp[(size_t)r * D + 4 * c] = o;
        }
    }
}

// ------- K2 (MFMA bf16): he = edges@We ; leaky ; logit ; ex ------------------
// Block: 256 thr = 4 waves. Tile: 64 edges (16/wave). Head h = 16-col N-tile.
#define BLK_E 64
__global__ __launch_bounds__(256) void k_edge_logits_mfma(
    const float* __restrict__ edges,
    const int* __restrict__ senders, const int* __restrict__ receivers,
    const float* __restrict__ We, const float* __restrict__ be,
    const float* __restrict__ a,
    const float* __restrict__ hs, const float* __restrict__ hr,
    float* __restrict__ ex)
{
    // padded pitch 136 bf16 (272 B) -> balanced LDS banks on b128 reads
    __shared__ __align__(16) unsigned short WeT[D][136];   // [col][k] 34816 B
    __shared__ __align__(16) unsigned short Et[BLK_E][136];// [edge][k] 17408 B
    int t = threadIdx.x;
    int lane = t & 63;
    int wv = t >> 6;      // wave 0..3
    int lg = lane >> 4;   // group 0..3
    int li = lane & 15;   // col-within-head / edge row

    // stage We^T as bf16 (transpose; once per block; coalesced reads)
    #pragma unroll 8
    for (int j = 0; j < 64; ++j) {
        int idx = t + 256 * j;     // 0..16383
        int k = idx >> 7, c = idx & 127;
        WeT[c][k] = f2bf_rne(We[idx]);
    }
    // per-lane loop-invariant head constants (col = h*16+li)
    float a_h[HEADS], be_h[HEADS];
    #pragma unroll
    for (int h = 0; h < HEADS; ++h) {
        a_h[h]  = a[h * 16 + li];
        be_h[h] = be[h * 16 + li];
    }

    const int ntiles = N_EDGES / BLK_E;   // 12500, exact
    for (int tile = blockIdx.x; tile < ntiles; tile += gridDim.x) {
        int e0 = tile * BLK_E;
        __syncthreads();   // prior Et reads done (and WeT staged, iter 0)
        {   // stage 64 edge rows -> bf16 LDS (coalesced float4 reads)
            const float4* Ev = (const float4*)(edges + (size_t)e0 * D);
            #pragma unroll
            for (int j = 0; j < 8; ++j) {
                int fi = t + 256 * j;        // float4 slot 0..2047
                float4 v = Ev[fi];
                int row = fi >> 5;           // 32 float4 per row
                int col = (fi & 31) * 4;
                ushort4 b;
                b.x = f2bf_rne(v.x); b.y = f2bf_rne(v.y);
                b.z = f2bf_rne(v.z); b.w = f2bf_rne(v.w);
                *(ushort4*)&Et[row][col] = b;
            }
        }
        __syncthreads();

        // A fragments: 16 edges of this wave, 4 K-blocks
        short8b afr[4];
        int erow = wv * 16 + li;
        #pragma unroll
        for (int kb = 0; kb < 4; ++kb)
            afr[kb] = *(const short8b*)&Et[erow][kb * 32 + lg * 8];

        // sender/receiver ids for the 4 rows this lane's C-regs cover
        int sj[4], rj[4];
        #pragma unroll
        for (int j = 0; j < 4; ++j) {
            int er = e0 + wv * 16 + lg * 4 + j;
            sj[j] = senders[er];
            rj[j] = receivers[er];
        }

        #pragma unroll 2
        for (int h = 0; h < HEADS; ++h) {
            f32x4 acc = {0.f, 0.f, 0.f, 0.f};
            #pragma unroll
            for (int kb = 0; kb < 4; ++kb) {
                short8b bfr = *(const short8b*)&WeT[h * 16 + li][kb * 32 + lg * 8];
                acc = __builtin_amdgcn_mfma_f32_16x16x32_bf16(afr[kb], bfr, acc, 0, 0, 0);
            }
            // C: col = h*16+li, row = lg*4 + j  -> x = he + be + hs[s] + hr[r]
            float p[4];
            #pragma unroll
            for (int j = 0; j < 4; ++j) {
                float x = acc[j] + be_h[h]
                        + hs[(size_t)sj[j] * D + h * 16 + li]
                        + hr[(size_t)rj[j] * D + h * 16 + li];
                x = x > 0.f ? x : 0.01f * x;
                p[j] = x * a_h[h];
            }
            #pragma unroll
            for (int j = 0; j < 4; ++j) {   // sum over the 16 cols of this head
                p[j] += __shfl_xor(p[j], 1);
                p[j] += __shfl_xor(p[j], 2);
                p[j] += __shfl_xor(p[j], 4);
                p[j] += __shfl_xor(p[j], 8);
            }
            if (li == 0) {
                #pragma unroll
                for (int j = 0; j < 4; ++j) {
                    int er = e0 + wv * 16 + lg * 4 + j;
                    ex[(size_t)er * HEADS + h] = __expf(p[j]);
                }
            }
        }
    }
}

// ------------------------- CSR build (per call) ------------------------------
__global__ __launch_bounds__(256) void k_hist(
    const int* __restrict__ receivers, int* __restrict__ deg)
{
    int i = blockIdx.x * 256 + threadIdx.x;
    if (i < N_EDGES) atomicAdd(&deg[receivers[i]], 1);
}

#define SCAN_CHUNK 49
__global__ __launch_bounds__(1024) void k_scan(
    const int* __restrict__ deg, int* __restrict__ rowptr, int* __restrict__ cursor)
{
    __shared__ int sm[1024];
    int t = threadIdx.x;
    int base = t * SCAN_CHUNK;
    int lsum = 0;
    #pragma unroll 4
    for (int i = 0; i < SCAN_CHUNK; ++i) {
        int idx = base + i;
        if (idx < N_NODES) lsum += deg[idx];
    }
    sm[t] = lsum;
    __syncthreads();
    for (int off = 1; off < 1024; off <<= 1) {
        int v = (t >= off) ? sm[t - off] : 0;
        __syncthreads();
        sm[t] += v;
        __syncthreads();
    }
    int run = (t > 0) ? sm[t - 1] : 0;
    for (int i = 0; i < SCAN_CHUNK; ++i) {
        int idx = base + i;
        if (idx < N_NODES) {
            rowptr[idx] = run;
            cursor[idx] = run;
            run += deg[idx];
        }
    }
    if (t == 1023) rowptr[N_NODES] = sm[1023];
}

__global__ __launch_bounds__(256) void k_fill(
    const int* __restrict__ receivers, int* __restrict__ cursor,
    int* __restrict__ eids)
{
    int i = blockIdx.x * 256 + threadIdx.x;
    if (i < N_EDGES) {
        int r = receivers[i];
        int pos = atomicAdd(&cursor[r], 1);
        eids[pos] = i;
    }
}

// ---------- K3: per-node gather: denom + weighted sum, write once -----------
__global__ __launch_bounds__(256) void k_gather_out(
    const int* __restrict__ rowptr, const int* __restrict__ eids,
    const int* __restrict__ senders,
    const float* __restrict__ hs, const float* __restrict__ ex,
    float* __restrict__ out)
{
    int r = blockIdx.x * 4 + (threadIdx.x >> 6);
    int l = threadIdx.x & 63;
    int h = l >> 3;
    int beg = rowptr[r], end = rowptr[r + 1];

    float dsum = 0.f;
    for (int j = beg + (l & 7); j < end; j += 8) {
        int e = eids[j];
        dsum += ex[(size_t)e * HEADS + h];
    }
    dsum += __shfl_xor(dsum, 1);
    dsum += __shfl_xor(dsum, 2);
    dsum += __shfl_xor(dsum, 4);
    float inv = 1.0f / dsum;

    float2 acc = make_float2(0.f, 0.f);
    for (int j = beg; j < end; ++j) {
        int e = eids[j];
        float w = ex[(size_t)e * HEADS + h] * inv;
        int s = senders[e];
        float2 hv = *(const float2*)&hs[(size_t)s * D + 2 * l];
        acc.x += w * hv.x;
        acc.y += w * hv.y;
    }
    *(float2*)&out[(size_t)r * D + 2 * l] = acc;
}

extern "C" void kernel_launch(void* const* d_in, const int* in_sizes, int n_in,
                              void* d_out, int out_size, void* d_ws, size_t ws_size,
                              hipStream_t stream) {
    const float* nodes     = (const float*)d_in[0];
    const float* edges     = (const float*)d_in[1];
    const int*   senders   = (const int*)d_in[2];
    const int*   receivers = (const int*)d_in[3];
    const float* Ws = (const float*)d_in[4];
    const float* bs = (const float*)d_in[5];
    const float* Wr = (const float*)d_in[6];
    const float* br = (const float*)d_in[7];
    const float* We = (const float*)d_in[8];
    const float* be = (const float*)d_in[9];
    const float* a  = (const float*)d_in[10];
    float* out = (float*)d_out;

    float* hs = (float*)d_ws;                         // 6.4M f32
    float* hr = hs + (size_t)N_NODES * D;             // 6.4M f32 (dead after K2)
    float* ex = hr + (size_t)N_NODES * D;             // 6.4M f32
    int* deg    = (int*)hr;                           // CSR reuses hr region
    int* rowptr = deg + N_NODES;
    int* cursor = rowptr + N_NODES + 1;
    int* eids   = cursor + N_NODES;

    int ntiles_n = (N_NODES + 31) / 32;
    k_node_proj<<<ntiles_n * 2, 256, 0, stream>>>(nodes, Ws, bs, Wr, br, hs, hr);
    k_edge_logits_mfma<<<2048, 256, 0, stream>>>(edges, senders, receivers, We, be, a,
                                                 hs, hr, ex);
    hipMemsetAsync(deg, 0, N_NODES * sizeof(int), stream);
    k_hist<<<N_EDGES / 256, 256, 0, stream>>>(receivers, deg);
    k_scan<<<1, 1024, 0, stream>>>(deg, rowptr, cursor);
    k_fill<<<N_EDGES / 256, 256, 0, stream>>>(receivers, cursor, eids);
    k_gather_out<<<N_NODES / 4, 256, 0, stream>>>(rowptr, eids, senders, hs, ex, out);
}

// Round 4
// 593.270 us; speedup vs baseline: 2.0629x; 1.1555x over previous
//
#include <hip/hip_runtime.h>

#define N_NODES 50000
#define N_EDGES 800000
#define D 128
#define HEADS 8

typedef __attribute__((ext_vector_type(8))) short short8b;  // 8 bf16 (4 VGPRs)
typedef __attribute__((ext_vector_type(4))) float f32x4;

__device__ __forceinline__ unsigned short f2bf_rne(float f) {
    unsigned int u = __float_as_uint(f);
    u += 0x7FFFu + ((u >> 16) & 1u);   // round-to-nearest-even
    return (unsigned short)(u >> 16);
}

// ---------------- K1: hs = nodes@Ws + bs ; hr = nodes@Wr + br ----------------
// 128 rows per block (4 sub-tiles) to amortize the 64KB W LDS load.
#define K1_ROWS 128
__global__ __launch_bounds__(256) void k_node_proj(
    const float* __restrict__ nodes,
    const float* __restrict__ Ws, const float* __restrict__ bs,
    const float* __restrict__ Wr, const float* __restrict__ br,
    float* __restrict__ hs, float* __restrict__ hr)
{
    __shared__ float Wl[D][D];    // 64 KB
    __shared__ float Al[32][D];   // 16 KB
    const int ntiles = (N_NODES + K1_ROWS - 1) / K1_ROWS;   // 391
    int bx = blockIdx.x;
    int proj = (bx >= ntiles) ? 1 : 0;
    int tile = proj ? (bx - ntiles) : bx;
    const float* W    = proj ? Wr : Ws;
    const float* bias = proj ? br : bs;
    float* outp       = proj ? hr : hs;
    int t = threadIdx.x;

    {   // load W -> LDS once per block
        const float4* Wv = (const float4*)W;
        float4* Wlv = (float4*)&Wl[0][0];
        #pragma unroll
        for (int j = 0; j < 16; ++j) Wlv[t + 256 * j] = Wv[t + 256 * j];
    }
    int c = t & 31;
    int g = t >> 5;
    float4 bv_pre = *(const float4*)&bias[4 * c];

    for (int sub = 0; sub < 4; ++sub) {
        int row0 = tile * K1_ROWS + sub * 32;
        if (row0 >= N_NODES) break;          // uniform across block
        __syncthreads();                      // W ready (iter0) / prior Al reads done
        {   // stage 32 node rows (guarded)
            const float4* Nv = (const float4*)nodes;
            float4* Alv = (float4*)&Al[0][0];
            #pragma unroll
            for (int j = 0; j < 4; ++j) {
                int idx = t + 256 * j;
                int r = row0 + (idx >> 5);
                float4 v = make_float4(0.f, 0.f, 0.f, 0.f);
                if (r < N_NODES) v = Nv[(size_t)r * 32 + (idx & 31)];
                Alv[idx] = v;
            }
        }
        __syncthreads();

        float acc[4][4];
        #pragma unroll
        for (int i = 0; i < 4; ++i)
            #pragma unroll
            for (int j = 0; j < 4; ++j) acc[i][j] = 0.f;

        #pragma unroll 4
        for (int k = 0; k < D; ++k) {
            float4 b4 = *(const float4*)&Wl[k][4 * c];
            #pragma unroll
            for (int i = 0; i < 4; ++i) {
                float av = Al[4 * g + i][k];
                acc[i][0] += av * b4.x; acc[i][1] += av * b4.y;
                acc[i][2] += av * b4.z; acc[i][3] += av * b4.w;
            }
        }
        #pragma unroll
        for (int i = 0; i < 4; ++i) {
            int r = row0 + 4 * g + i;
            if (r < N_NODES) {
                float4 o;
                o.x = acc[i][0] + bv_pre.x; o.y = acc[i][1] + bv_pre.y;
                o.z = acc[i][2] + bv_pre.z; o.w = acc[i][3] + bv_pre.w;
                *(float4*)&outp[(size_t)r * D + 4 * c] = o;
            }
        }
    }
}

// ------- K2 (MFMA bf16): he = edges@We ; leaky ; logit ; ex ------------------
// 4 waves/block, 64 edges/tile (16/wave). Head h = one 16-col MFMA N-tile.
// All hs/hr gathers hoisted into registers (64 loads in flight) for MLP.
#define BLK_E 64
__global__ __launch_bounds__(256, 3) void k_edge_logits_mfma(
    const float* __restrict__ edges,
    const int* __restrict__ senders, const int* __restrict__ receivers,
    const float* __restrict__ We, const float* __restrict__ be,
    const float* __restrict__ a,
    const float* __restrict__ hs, const float* __restrict__ hr,
    float* __restrict__ ex)
{
    __shared__ __align__(16) unsigned short WeT[D][136];    // [col][k] 34816 B
    __shared__ __align__(16) unsigned short Et[BLK_E][136]; // [edge][k] 17408 B
    int t = threadIdx.x;
    int lane = t & 63;
    int wv = t >> 6;      // wave 0..3
    int lg = lane >> 4;   // group 0..3
    int li = lane & 15;   // col-within-head / edge row

    // stage We^T as bf16 (once per block)
    #pragma unroll 8
    for (int j = 0; j < 64; ++j) {
        int idx = t + 256 * j;     // 0..16383
        int k = idx >> 7, c = idx & 127;
        WeT[c][k] = f2bf_rne(We[idx]);
    }
    float a_h[HEADS], be_h[HEADS];
    #pragma unroll
    for (int h = 0; h < HEADS; ++h) {
        a_h[h]  = a[h * 16 + li];
        be_h[h] = be[h * 16 + li];
    }

    const int ntiles = N_EDGES / BLK_E;   // 12500, exact
    for (int tile = blockIdx.x; tile < ntiles; tile += gridDim.x) {
        int e0 = tile * BLK_E;

        // sender/receiver ids for the 4 C-rows this lane covers (issue first)
        int sj[4], rj[4];
        #pragma unroll
        for (int j = 0; j < 4; ++j) {
            int er = e0 + wv * 16 + lg * 4 + j;
            sj[j] = senders[er];
            rj[j] = receivers[er];
        }

        __syncthreads();   // prior Et reads done (and WeT staged, iter 0)
        {   // stage 64 edge rows -> bf16 LDS
            const float4* Ev = (const float4*)(edges + (size_t)e0 * D);
            #pragma unroll
            for (int j = 0; j < 8; ++j) {
                int fi = t + 256 * j;        // float4 slot 0..2047
                float4 v = Ev[fi];
                int row = fi >> 5;
                int col = (fi & 31) * 4;
                ushort4 b;
                b.x = f2bf_rne(v.x); b.y = f2bf_rne(v.y);
                b.z = f2bf_rne(v.z); b.w = f2bf_rne(v.w);
                *(ushort4*)&Et[row][col] = b;
            }
        }

        // hoisted gathers: 64 independent dword loads, in flight across the
        // barrier (register loads need not drain at s_barrier)
        float g_hs[4][HEADS], g_hr[4][HEADS];
        #pragma unroll
        for (int j = 0; j < 4; ++j) {
            const float* hsrow = hs + (size_t)sj[j] * D + li;
            const float* hrrow = hr + (size_t)rj[j] * D + li;
            #pragma unroll
            for (int h = 0; h < HEADS; ++h) {
                g_hs[j][h] = hsrow[h * 16];
                g_hr[j][h] = hrrow[h * 16];
            }
        }

        __syncthreads();   // Et ready

        short8b afr[4];
        int erow = wv * 16 + li;
        #pragma unroll
        for (int kb = 0; kb < 4; ++kb)
            afr[kb] = *(const short8b*)&Et[erow][kb * 32 + lg * 8];

        #pragma unroll
        for (int h = 0; h < HEADS; ++h) {
            f32x4 acc = {0.f, 0.f, 0.f, 0.f};
            #pragma unroll
            for (int kb = 0; kb < 4; ++kb) {
                short8b bfr = *(const short8b*)&WeT[h * 16 + li][kb * 32 + lg * 8];
                acc = __builtin_amdgcn_mfma_f32_16x16x32_bf16(afr[kb], bfr, acc, 0, 0, 0);
            }
            float p[4];
            #pragma unroll
            for (int j = 0; j < 4; ++j) {
                float x = acc[j] + be_h[h] + g_hs[j][h] + g_hr[j][h];
                x = x > 0.f ? x : 0.01f * x;
                p[j] = x * a_h[h];
            }
            #pragma unroll
            for (int j = 0; j < 4; ++j) {
                p[j] += __shfl_xor(p[j], 1);
                p[j] += __shfl_xor(p[j], 2);
                p[j] += __shfl_xor(p[j], 4);
                p[j] += __shfl_xor(p[j], 8);
            }
            if (li == 0) {
                #pragma unroll
                for (int j = 0; j < 4; ++j) {
                    int er = e0 + wv * 16 + lg * 4 + j;
                    ex[(size_t)er * HEADS + h] = __expf(p[j]);
                }
            }
        }
    }
}

// ------------------------- CSR build (per call) ------------------------------
__global__ __launch_bounds__(256) void k_hist(
    const int* __restrict__ receivers, int* __restrict__ deg)
{
    int i = blockIdx.x * 256 + threadIdx.x;
    if (i < N_EDGES) atomicAdd(&deg[receivers[i]], 1);
}

#define SCAN_CHUNK 49
__global__ __launch_bounds__(1024) void k_scan(
    const int* __restrict__ deg, int* __restrict__ rowptr, int* __restrict__ cursor)
{
    __shared__ int sm[1024];
    int t = threadIdx.x;
    int base = t * SCAN_CHUNK;
    int lsum = 0;
    #pragma unroll 4
    for (int i = 0; i < SCAN_CHUNK; ++i) {
        int idx = base + i;
        if (idx < N_NODES) lsum += deg[idx];
    }
    sm[t] = lsum;
    __syncthreads();
    for (int off = 1; off < 1024; off <<= 1) {
        int v = (t >= off) ? sm[t - off] : 0;
        __syncthreads();
        sm[t] += v;
        __syncthreads();
    }
    int run = (t > 0) ? sm[t - 1] : 0;
    for (int i = 0; i < SCAN_CHUNK; ++i) {
        int idx = base + i;
        if (idx < N_NODES) {
            rowptr[idx] = run;
            cursor[idx] = run;
            run += deg[idx];
        }
    }
    if (t == 1023) rowptr[N_NODES] = sm[1023];
}

__global__ __launch_bounds__(256) void k_fill(
    const int* __restrict__ receivers, int* __restrict__ cursor,
    int* __restrict__ eids)
{
    int i = blockIdx.x * 256 + threadIdx.x;
    if (i < N_EDGES) {
        int r = receivers[i];
        int pos = atomicAdd(&cursor[r], 1);
        eids[pos] = i;
    }
}

// ---------- K3: per-node gather, 8-wide software pipeline --------------------
__global__ __launch_bounds__(256) void k_gather_out(
    const int* __restrict__ rowptr, const int* __restrict__ eids,
    const int* __restrict__ senders,
    const float* __restrict__ hs, const float* __restrict__ ex,
    float* __restrict__ out)
{
    int r = blockIdx.x * 4 + (threadIdx.x >> 6);
    int l = threadIdx.x & 63;
    int h = l >> 3;
    int beg = rowptr[r], end = rowptr[r + 1];

    // pass 1: per-head denom (8 lanes per head split the edges)
    float dsum = 0.f;
    for (int j = beg + (l & 7); j < end; j += 8) {
        int e = eids[j];
        dsum += ex[(size_t)e * HEADS + h];
    }
    dsum += __shfl_xor(dsum, 1);
    dsum += __shfl_xor(dsum, 2);
    dsum += __shfl_xor(dsum, 4);
    float oscale = (end > beg) ? (1.0f / dsum) : 0.f;

    // pass 2: batched 8-wide stages for MLP (indices -> senders/ex -> hs rows)
    float2 acc = make_float2(0.f, 0.f);
    for (int j0 = beg; j0 < end; j0 += 8) {
        int cnt = end - j0;           // >=1
        int e[8], s[8]; float w[8];
        #pragma unroll
        for (int q = 0; q < 8; ++q)
            if (q < cnt) e[q] = eids[j0 + q];
        #pragma unroll
        for (int q = 0; q < 8; ++q)
            if (q < cnt) { s[q] = senders[e[q]]; w[q] = ex[(size_t)e[q] * HEADS + h]; }
        #pragma unroll
        for (int q = 0; q < 8; ++q)
            if (q < cnt) {
                float2 hv = *(const float2*)&hs[(size_t)s[q] * D + 2 * l];
                acc.x += w[q] * hv.x;
                acc.y += w[q] * hv.y;
            }
    }
    acc.x *= oscale; acc.y *= oscale;
    *(float2*)&out[(size_t)r * D + 2 * l] = acc;
}

extern "C" void kernel_launch(void* const* d_in, const int* in_sizes, int n_in,
                              void* d_out, int out_size, void* d_ws, size_t ws_size,
                              hipStream_t stream) {
    const float* nodes     = (const float*)d_in[0];
    const float* edges     = (const float*)d_in[1];
    const int*   senders   = (const int*)d_in[2];
    const int*   receivers = (const int*)d_in[3];
    const float* Ws = (const float*)d_in[4];
    const float* bs = (const float*)d_in[5];
    const float* Wr = (const float*)d_in[6];
    const float* br = (const float*)d_in[7];
    const float* We = (const float*)d_in[8];
    const float* be = (const float*)d_in[9];
    const float* a  = (const float*)d_in[10];
    float* out = (float*)d_out;

    float* hs = (float*)d_ws;                         // 6.4M f32
    float* hr = hs + (size_t)N_NODES * D;             // 6.4M f32 (dead after K2)
    float* ex = hr + (size_t)N_NODES * D;             // 6.4M f32
    int* deg    = (int*)hr;                           // CSR reuses hr region
    int* rowptr = deg + N_NODES;
    int* cursor = rowptr + N_NODES + 1;
    int* eids   = cursor + N_NODES;

    int ntiles_n = (N_NODES + K1_ROWS - 1) / K1_ROWS;
    k_node_proj<<<ntiles_n * 2, 256, 0, stream>>>(nodes, Ws, bs, Wr, br, hs, hr);
    k_edge_logits_mfma<<<2048, 256, 0, stream>>>(edges, senders, receivers, We, be, a,
                                                 hs, hr, ex);
    hipMemsetAsync(deg, 0, N_NODES * sizeof(int), stream);
    k_hist<<<N_EDGES / 256, 256, 0, stream>>>(receivers, deg);
    k_scan<<<1, 1024, 0, stream>>>(deg, rowptr, cursor);
    k_fill<<<N_EDGES / 256, 256, 0, stream>>>(receivers, cursor, eids);
    k_gather_out<<<N_NODES / 4, 256, 0, stream>>>(rowptr, eids, senders, hs, ex, out);
}

// Round 5
// 486.939 us; speedup vs baseline: 2.5134x; 1.2184x over previous
//
#include <hip/hip_runtime.h>

#define N_NODES 50000
#define N_EDGES 800000
#define D 128
#define HEADS 8

typedef __attribute__((ext_vector_type(8))) short short8b;  // 8 bf16 (4 VGPRs)
typedef __attribute__((ext_vector_type(4))) float f32x4;

__device__ __forceinline__ unsigned short f2bf_rne(float f) {
    unsigned int u = __float_as_uint(f);
    u += 0x7FFFu + ((u >> 16) & 1u);   // round-to-nearest-even
    return (unsigned short)(u >> 16);
}
__device__ __forceinline__ float bf2f(unsigned short u) {
    return __uint_as_float(((unsigned int)u) << 16);
}

// ---------------- K1 (MFMA): hs/hr = bf16(nodes @ W + b) --------------------
// Block handles one projection x 256 rows (4 sub-tiles of 64). W staged once.
#define K1_ROWS 256
__global__ __launch_bounds__(256, 3) void k_node_proj_mfma(
    const float* __restrict__ nodes,
    const float* __restrict__ Ws, const float* __restrict__ bs,
    const float* __restrict__ Wr, const float* __restrict__ br,
    unsigned short* __restrict__ hsb, unsigned short* __restrict__ hrb)
{
    __shared__ __align__(16) unsigned short WT[D][136];   // [col][k] 34816 B
    __shared__ __align__(16) unsigned short At[64][136];  // [row][k] 17408 B
    const int ntiles = (N_NODES + K1_ROWS - 1) / K1_ROWS;   // 196
    int bx = blockIdx.x;
    int proj = (bx >= ntiles) ? 1 : 0;
    int tile = proj ? (bx - ntiles) : bx;
    const float* W    = proj ? Wr : Ws;
    const float* bias = proj ? br : bs;
    unsigned short* outp = proj ? hrb : hsb;
    int t = threadIdx.x;
    int lane = t & 63;
    int wv = t >> 6;      // wave 0..3
    int lg = lane >> 4;   // 0..3
    int li = lane & 15;

    // stage W^T bf16 (once per block)
    #pragma unroll 8
    for (int j = 0; j < 64; ++j) {
        int idx = t + 256 * j;     // 0..16383 = k*128+c
        int k = idx >> 7, c = idx & 127;
        WT[c][k] = f2bf_rne(W[idx]);
    }
    float b_ct[8];
    #pragma unroll
    for (int ct = 0; ct < 8; ++ct) b_ct[ct] = bias[ct * 16 + li];

    #pragma unroll 1
    for (int sub = 0; sub < 4; ++sub) {
        int row0 = tile * K1_ROWS + sub * 64;
        if (row0 >= N_NODES) break;          // uniform
        __syncthreads();                      // WT ready / prior At reads done
        {   // stage 64 node rows -> bf16 LDS
            const float4* Nv = (const float4*)nodes;
            #pragma unroll
            for (int j = 0; j < 8; ++j) {
                int fi = t + 256 * j;        // float4 slot 0..2047
                int r = row0 + (fi >> 5);
                float4 v = make_float4(0.f, 0.f, 0.f, 0.f);
                if (r < N_NODES) v = Nv[(size_t)r * 32 + (fi & 31)];
                ushort4 b;
                b.x = f2bf_rne(v.x); b.y = f2bf_rne(v.y);
                b.z = f2bf_rne(v.z); b.w = f2bf_rne(v.w);
                *(ushort4*)&At[fi >> 5][(fi & 31) * 4] = b;
            }
        }
        __syncthreads();

        short8b afr[4];
        #pragma unroll
        for (int kb = 0; kb < 4; ++kb)
            afr[kb] = *(const short8b*)&At[wv * 16 + li][kb * 32 + lg * 8];

        #pragma unroll
        for (int ct = 0; ct < 8; ++ct) {      // 16-col output tiles
            f32x4 acc = {0.f, 0.f, 0.f, 0.f};
            #pragma unroll
            for (int kb = 0; kb < 4; ++kb) {
                short8b bfr = *(const short8b*)&WT[ct * 16 + li][kb * 32 + lg * 8];
                acc = __builtin_amdgcn_mfma_f32_16x16x32_bf16(afr[kb], bfr, acc, 0, 0, 0);
            }
            #pragma unroll
            for (int j = 0; j < 4; ++j) {
                int r = row0 + wv * 16 + lg * 4 + j;
                if (r < N_NODES)
                    outp[(size_t)r * D + ct * 16 + li] = f2bf_rne(acc[j] + b_ct[ct]);
            }
        }
    }
}

// ------- K2 (MFMA bf16): he = edges@We ; leaky ; logit ; ex ------------------
#define BLK_E 64
__global__ __launch_bounds__(256, 3) void k_edge_logits_mfma(
    const float* __restrict__ edges,
    const int* __restrict__ senders, const int* __restrict__ receivers,
    const float* __restrict__ We, const float* __restrict__ be,
    const float* __restrict__ a,
    const unsigned short* __restrict__ hsb, const unsigned short* __restrict__ hrb,
    float* __restrict__ ex)
{
    __shared__ __align__(16) unsigned short WeT[D][136];    // [col][k]
    __shared__ __align__(16) unsigned short Et[BLK_E][136]; // [edge][k]
    int t = threadIdx.x;
    int lane = t & 63;
    int wv = t >> 6;
    int lg = lane >> 4;
    int li = lane & 15;

    #pragma unroll 8
    for (int j = 0; j < 64; ++j) {
        int idx = t + 256 * j;
        int k = idx >> 7, c = idx & 127;
        WeT[c][k] = f2bf_rne(We[idx]);
    }
    float a_h[HEADS], be_h[HEADS];
    #pragma unroll
    for (int h = 0; h < HEADS; ++h) {
        a_h[h]  = a[h * 16 + li];
        be_h[h] = be[h * 16 + li];
    }
    int jm = li & 3;

    const int ntiles = N_EDGES / BLK_E;   // 12500
    for (int tile = blockIdx.x; tile < ntiles; tile += gridDim.x) {
        int e0 = tile * BLK_E;

        int sj[4], rj[4];
        #pragma unroll
        for (int j = 0; j < 4; ++j) {
            int er = e0 + wv * 16 + lg * 4 + j;
            sj[j] = senders[er];
            rj[j] = receivers[er];
        }

        __syncthreads();   // prior Et reads done
        {   // stage 64 edge rows -> bf16 LDS
            const float4* Ev = (const float4*)(edges + (size_t)e0 * D);
            #pragma unroll
            for (int j = 0; j < 8; ++j) {
                int fi = t + 256 * j;
                float4 v = Ev[fi];
                ushort4 b;
                b.x = f2bf_rne(v.x); b.y = f2bf_rne(v.y);
                b.z = f2bf_rne(v.z); b.w = f2bf_rne(v.w);
                *(ushort4*)&Et[fi >> 5][(fi & 31) * 4] = b;
            }
        }

        // hoisted bf16 gathers (64 independent loads in flight across barrier)
        unsigned short g_hs[4][HEADS], g_hr[4][HEADS];
        #pragma unroll
        for (int j = 0; j < 4; ++j) {
            const unsigned short* hsrow = hsb + (size_t)sj[j] * D + li;
            const unsigned short* hrrow = hrb + (size_t)rj[j] * D + li;
            #pragma unroll
            for (int h = 0; h < HEADS; ++h) {
                g_hs[j][h] = hsrow[h * 16];
                g_hr[j][h] = hrrow[h * 16];
            }
        }

        __syncthreads();   // Et ready

        short8b afr[4];
        int erow = wv * 16 + li;
        #pragma unroll
        for (int kb = 0; kb < 4; ++kb)
            afr[kb] = *(const short8b*)&Et[erow][kb * 32 + lg * 8];

        #pragma unroll
        for (int h = 0; h < HEADS; ++h) {
            f32x4 acc = {0.f, 0.f, 0.f, 0.f};
            #pragma unroll
            for (int kb = 0; kb < 4; ++kb) {
                short8b bfr = *(const short8b*)&WeT[h * 16 + li][kb * 32 + lg * 8];
                acc = __builtin_amdgcn_mfma_f32_16x16x32_bf16(afr[kb], bfr, acc, 0, 0, 0);
            }
            float p[4];
            #pragma unroll
            for (int j = 0; j < 4; ++j) {
                float x = acc[j] + be_h[h] + bf2f(g_hs[j][h]) + bf2f(g_hr[j][h]);
                x = x > 0.f ? x : 0.01f * x;
                p[j] = x * a_h[h];
            }
            // reduce over 16 lanes; j-select after 2 steps (10 shfls vs 16)
            #pragma unroll
            for (int j = 0; j < 4; ++j) {
                p[j] += __shfl_xor(p[j], 1);
                p[j] += __shfl_xor(p[j], 2);
            }
            float q = (jm & 1) ? ((jm & 2) ? p[3] : p[1])
                               : ((jm & 2) ? p[2] : p[0]);
            q += __shfl_xor(q, 4);
            q += __shfl_xor(q, 8);
            float e_ = __expf(q);     // all lanes; lanes li<4 hold j=li
            if (li < 4) {
                int er = e0 + wv * 16 + lg * 4 + li;
                ex[(size_t)er * HEADS + h] = e_;
            }
        }
    }
}

// ------------------------- CSR build (per call) ------------------------------
__global__ __launch_bounds__(256) void k_hist(
    const int* __restrict__ receivers, int* __restrict__ deg)
{
    int i = blockIdx.x * 256 + threadIdx.x;
    if (i < N_EDGES) atomicAdd(&deg[receivers[i]], 1);
}

#define SCAN_CHUNK 49
__global__ __launch_bounds__(1024) void k_scan(
    const int* __restrict__ deg, int* __restrict__ rowptr, int* __restrict__ cursor)
{
    __shared__ int sm[1024];
    int t = threadIdx.x;
    int base = t * SCAN_CHUNK;
    int lsum = 0;
    #pragma unroll 4
    for (int i = 0; i < SCAN_CHUNK; ++i) {
        int idx = base + i;
        if (idx < N_NODES) lsum += deg[idx];
    }
    sm[t] = lsum;
    __syncthreads();
    for (int off = 1; off < 1024; off <<= 1) {
        int v = (t >= off) ? sm[t - off] : 0;
        __syncthreads();
        sm[t] += v;
        __syncthreads();
    }
    int run = (t > 0) ? sm[t - 1] : 0;
    for (int i = 0; i < SCAN_CHUNK; ++i) {
        int idx = base + i;
        if (idx < N_NODES) {
            rowptr[idx] = run;
            cursor[idx] = run;
            run += deg[idx];
        }
    }
    if (t == 1023) rowptr[N_NODES] = sm[1023];
}

__global__ __launch_bounds__(256) void k_fill(
    const int* __restrict__ receivers, int* __restrict__ cursor,
    int* __restrict__ eids)
{
    int i = blockIdx.x * 256 + threadIdx.x;
    if (i < N_EDGES) {
        int r = receivers[i];
        int pos = atomicAdd(&cursor[r], 1);
        eids[pos] = i;
    }
}

// ---------- K3: per-node single-pass gather: out = (Σ ex·hs)/Σ ex -----------
__global__ __launch_bounds__(256) void k_gather_out(
    const int* __restrict__ rowptr, const int* __restrict__ eids,
    const int* __restrict__ senders,
    const unsigned short* __restrict__ hsb, const float* __restrict__ ex,
    float* __restrict__ out)
{
    int r = blockIdx.x * 4 + (threadIdx.x >> 6);
    int l = threadIdx.x & 63;
    int h = l >> 3;
    int beg = rowptr[r], end = rowptr[r + 1];

    float2 acc = make_float2(0.f, 0.f);
    float dsum = 0.f;   // every lane redundantly sums its head's denom
    for (int j0 = beg; j0 < end; j0 += 8) {
        int cnt = end - j0;
        int e[8], s[8]; float w[8];
        #pragma unroll
        for (int q = 0; q < 8; ++q)
            if (q < cnt) e[q] = eids[j0 + q];
        #pragma unroll
        for (int q = 0; q < 8; ++q)
            if (q < cnt) { s[q] = senders[e[q]]; w[q] = ex[(size_t)e[q] * HEADS + h]; }
        #pragma unroll
        for (int q = 0; q < 8; ++q)
            if (q < cnt) {
                ushort2 hv = *(const ushort2*)&hsb[(size_t)s[q] * D + 2 * l];
                acc.x += w[q] * bf2f(hv.x);
                acc.y += w[q] * bf2f(hv.y);
                dsum  += w[q];
            }
    }
    float inv = (end > beg && dsum != 0.f) ? (1.0f / dsum) : 0.f;
    acc.x *= inv; acc.y *= inv;
    *(float2*)&out[(size_t)r * D + 2 * l] = acc;
}

extern "C" void kernel_launch(void* const* d_in, const int* in_sizes, int n_in,
                              void* d_out, int out_size, void* d_ws, size_t ws_size,
                              hipStream_t stream) {
    const float* nodes     = (const float*)d_in[0];
    const float* edges     = (const float*)d_in[1];
    const int*   senders   = (const int*)d_in[2];
    const int*   receivers = (const int*)d_in[3];
    const float* Ws = (const float*)d_in[4];
    const float* bs = (const float*)d_in[5];
    const float* Wr = (const float*)d_in[6];
    const float* br = (const float*)d_in[7];
    const float* We = (const float*)d_in[8];
    const float* be = (const float*)d_in[9];
    const float* a  = (const float*)d_in[10];
    float* out = (float*)d_out;

    unsigned short* hsb = (unsigned short*)d_ws;          // 6.4M bf16 (12.8 MB)
    unsigned short* hrb = hsb + (size_t)N_NODES * D;      // 6.4M bf16
    float* ex   = (float*)(hrb + (size_t)N_NODES * D);    // 6.4M f32
    int* deg    = (int*)(ex + (size_t)N_EDGES * HEADS);   // 50000
    int* rowptr = deg + N_NODES;                          // 50001
    int* cursor = rowptr + N_NODES + 1;                   // 50000
    int* eids   = cursor + N_NODES;                       // 800000

    int ntiles_n = (N_NODES + K1_ROWS - 1) / K1_ROWS;
    k_node_proj_mfma<<<ntiles_n * 2, 256, 0, stream>>>(nodes, Ws, bs, Wr, br, hsb, hrb);
    k_edge_logits_mfma<<<2048, 256, 0, stream>>>(edges, senders, receivers, We, be, a,
                                                 hsb, hrb, ex);
    hipMemsetAsync(deg, 0, N_NODES * sizeof(int), stream);
    k_hist<<<N_EDGES / 256, 256, 0, stream>>>(receivers, deg);
    k_scan<<<1, 1024, 0, stream>>>(deg, rowptr, cursor);
    k_fill<<<N_EDGES / 256, 256, 0, stream>>>(receivers, cursor, eids);
    k_gather_out<<<N_NODES / 4, 256, 0, stream>>>(rowptr, eids, senders, hsb, ex, out);
}

// Round 6
// 463.207 us; speedup vs baseline: 2.6422x; 1.0512x over previous
//
#include <hip/hip_runtime.h>

#define N_NODES 50000
#define N_EDGES 800000
#define D 128
#define HEADS 8

typedef __attribute__((ext_vector_type(8))) short short8b;  // 8 bf16 (4 VGPRs)
typedef __attribute__((ext_vector_type(4))) float f32x4;

__device__ __forceinline__ unsigned short f2bf_rne(float f) {
    unsigned int u = __float_as_uint(f);
    u += 0x7FFFu + ((u >> 16) & 1u);   // round-to-nearest-even
    return (unsigned short)(u >> 16);
}
__device__ __forceinline__ float bf2f(unsigned short u) {
    return __uint_as_float(((unsigned int)u) << 16);
}

// ---------------- K1 (MFMA): hs/hr = bf16(nodes @ W + b) --------------------
#define K1_ROWS 256
__global__ __launch_bounds__(256, 3) void k_node_proj_mfma(
    const float* __restrict__ nodes,
    const float* __restrict__ Ws, const float* __restrict__ bs,
    const float* __restrict__ Wr, const float* __restrict__ br,
    unsigned short* __restrict__ hsb, unsigned short* __restrict__ hrb)
{
    __shared__ __align__(16) unsigned short WT[D][136];   // [col][k] 34816 B
    __shared__ __align__(16) unsigned short At[64][136];  // [row][k] 17408 B
    const int ntiles = (N_NODES + K1_ROWS - 1) / K1_ROWS;   // 196
    int bx = blockIdx.x;
    int proj = (bx >= ntiles) ? 1 : 0;
    int tile = proj ? (bx - ntiles) : bx;
    const float* W    = proj ? Wr : Ws;
    const float* bias = proj ? br : bs;
    unsigned short* outp = proj ? hrb : hsb;
    int t = threadIdx.x;
    int lane = t & 63;
    int wv = t >> 6;
    int lg = lane >> 4;
    int li = lane & 15;

    #pragma unroll 8
    for (int j = 0; j < 64; ++j) {
        int idx = t + 256 * j;     // k*128+c
        int k = idx >> 7, c = idx & 127;
        WT[c][k] = f2bf_rne(W[idx]);
    }
    float b_ct[8];
    #pragma unroll
    for (int ct = 0; ct < 8; ++ct) b_ct[ct] = bias[ct * 16 + li];

    #pragma unroll 1
    for (int sub = 0; sub < 4; ++sub) {
        int row0 = tile * K1_ROWS + sub * 64;
        if (row0 >= N_NODES) break;          // uniform
        __syncthreads();
        {   // stage 64 node rows -> bf16 LDS
            const float4* Nv = (const float4*)nodes;
            #pragma unroll
            for (int j = 0; j < 8; ++j) {
                int fi = t + 256 * j;
                int r = row0 + (fi >> 5);
                float4 v = make_float4(0.f, 0.f, 0.f, 0.f);
                if (r < N_NODES) v = Nv[(size_t)r * 32 + (fi & 31)];
                ushort4 b;
                b.x = f2bf_rne(v.x); b.y = f2bf_rne(v.y);
                b.z = f2bf_rne(v.z); b.w = f2bf_rne(v.w);
                *(ushort4*)&At[fi >> 5][(fi & 31) * 4] = b;
            }
        }
        __syncthreads();

        short8b afr[4];
        #pragma unroll
        for (int kb = 0; kb < 4; ++kb)
            afr[kb] = *(const short8b*)&At[wv * 16 + li][kb * 32 + lg * 8];

        #pragma unroll
        for (int ct = 0; ct < 8; ++ct) {
            f32x4 acc = {0.f, 0.f, 0.f, 0.f};
            #pragma unroll
            for (int kb = 0; kb < 4; ++kb) {
                short8b bfr = *(const short8b*)&WT[ct * 16 + li][kb * 32 + lg * 8];
                acc = __builtin_amdgcn_mfma_f32_16x16x32_bf16(afr[kb], bfr, acc, 0, 0, 0);
            }
            #pragma unroll
            for (int j = 0; j < 4; ++j) {
                int r = row0 + wv * 16 + lg * 4 + j;
                if (r < N_NODES)
                    outp[(size_t)r * D + ct * 16 + li] = f2bf_rne(acc[j] + b_ct[ct]);
            }
        }
    }
}

// ------------------------- CSR build (runs before K2) ------------------------
__global__ __launch_bounds__(256) void k_hist(
    const int* __restrict__ receivers, int* __restrict__ deg)
{
    int i = blockIdx.x * 256 + threadIdx.x;
    if (i < N_EDGES) atomicAdd(&deg[receivers[i]], 1);
}

#define SCAN_CHUNK 49
__global__ __launch_bounds__(1024) void k_scan(
    const int* __restrict__ deg, int* __restrict__ rowptr, int* __restrict__ cursor)
{
    __shared__ int sm[1024];
    int t = threadIdx.x;
    int base = t * SCAN_CHUNK;
    int lsum = 0;
    #pragma unroll 4
    for (int i = 0; i < SCAN_CHUNK; ++i) {
        int idx = base + i;
        if (idx < N_NODES) lsum += deg[idx];
    }
    sm[t] = lsum;
    __syncthreads();
    for (int off = 1; off < 1024; off <<= 1) {
        int v = (t >= off) ? sm[t - off] : 0;
        __syncthreads();
        sm[t] += v;
        __syncthreads();
    }
    int run = (t > 0) ? sm[t - 1] : 0;
    for (int i = 0; i < SCAN_CHUNK; ++i) {
        int idx = base + i;
        if (idx < N_NODES) {
            rowptr[idx] = run;
            cursor[idx] = run;
            run += deg[idx];
        }
    }
    if (t == 1023) rowptr[N_NODES] = sm[1023];
}

__global__ __launch_bounds__(256) void k_fill(
    const int* __restrict__ receivers, const int* __restrict__ senders,
    int* __restrict__ cursor,
    int* __restrict__ eids, int* __restrict__ s_csr, int* __restrict__ r_csr)
{
    int i = blockIdx.x * 256 + threadIdx.x;
    if (i < N_EDGES) {
        int r = receivers[i];
        int pos = atomicAdd(&cursor[r], 1);
        eids[pos]  = i;
        s_csr[pos] = senders[i];
        r_csr[pos] = r;
    }
}

// ------- K2 (MFMA bf16, CSR order): he=edges@We ; leaky ; logit ; ex --------
// Edges processed in receiver-sorted order: hr gathers hit L1 (r nearly
// constant within a 16-edge wave-tile), ex writes are CSR-contiguous.
#define BLK_E 64
__global__ __launch_bounds__(256, 3) void k_edge_logits_mfma(
    const float* __restrict__ edges,
    const int* __restrict__ eids, const int* __restrict__ s_csr,
    const int* __restrict__ r_csr,
    const float* __restrict__ We, const float* __restrict__ be,
    const float* __restrict__ a,
    const unsigned short* __restrict__ hsb, const unsigned short* __restrict__ hrb,
    float* __restrict__ ex)
{
    __shared__ __align__(16) unsigned short WeT[D][136];    // [col][k]
    __shared__ __align__(16) unsigned short Et[BLK_E][136]; // [edge][k]
    int t = threadIdx.x;
    int lane = t & 63;
    int wv = t >> 6;
    int lg = lane >> 4;
    int li = lane & 15;

    #pragma unroll 8
    for (int j = 0; j < 64; ++j) {
        int idx = t + 256 * j;
        int k = idx >> 7, c = idx & 127;
        WeT[c][k] = f2bf_rne(We[idx]);
    }
    float a_h[HEADS], be_h[HEADS];
    #pragma unroll
    for (int h = 0; h < HEADS; ++h) {
        a_h[h]  = a[h * 16 + li];
        be_h[h] = be[h * 16 + li];
    }
    int jm = li & 3;

    const int ntiles = N_EDGES / BLK_E;   // 12500
    for (int tile = blockIdx.x; tile < ntiles; tile += gridDim.x) {
        int p0 = tile * BLK_E;

        // this lane's 4 CSR rows: sender/receiver (coalesced/broadcast reads)
        int sj[4], rj[4];
        #pragma unroll
        for (int j = 0; j < 4; ++j) {
            int pos = p0 + wv * 16 + lg * 4 + j;
            sj[j] = s_csr[pos];
            rj[j] = r_csr[pos];
        }

        __syncthreads();   // prior Et reads done
        {   // stage 64 CSR-ordered edge rows -> bf16 LDS (row-gathered float4)
            const float4* Ev = (const float4*)edges;
            #pragma unroll
            for (int j = 0; j < 8; ++j) {
                int fi = t + 256 * j;
                int e = eids[p0 + (fi >> 5)];
                float4 v = Ev[(size_t)e * 32 + (fi & 31)];
                ushort4 b;
                b.x = f2bf_rne(v.x); b.y = f2bf_rne(v.y);
                b.z = f2bf_rne(v.z); b.w = f2bf_rne(v.w);
                *(ushort4*)&Et[fi >> 5][(fi & 31) * 4] = b;
            }
        }

        // hoisted gathers: hs random (L2/L3), hr mostly L1 (CSR locality)
        unsigned short g_hs[4][HEADS], g_hr[4][HEADS];
        #pragma unroll
        for (int j = 0; j < 4; ++j) {
            const unsigned short* hsrow = hsb + (size_t)sj[j] * D + li;
            const unsigned short* hrrow = hrb + (size_t)rj[j] * D + li;
            #pragma unroll
            for (int h = 0; h < HEADS; ++h) {
                g_hs[j][h] = hsrow[h * 16];
                g_hr[j][h] = hrrow[h * 16];
            }
        }

        __syncthreads();   // Et ready

        short8b afr[4];
        int erow = wv * 16 + li;
        #pragma unroll
        for (int kb = 0; kb < 4; ++kb)
            afr[kb] = *(const short8b*)&Et[erow][kb * 32 + lg * 8];

        #pragma unroll
        for (int h = 0; h < HEADS; ++h) {
            f32x4 acc = {0.f, 0.f, 0.f, 0.f};
            #pragma unroll
            for (int kb = 0; kb < 4; ++kb) {
                short8b bfr = *(const short8b*)&WeT[h * 16 + li][kb * 32 + lg * 8];
                acc = __builtin_amdgcn_mfma_f32_16x16x32_bf16(afr[kb], bfr, acc, 0, 0, 0);
            }
            float p[4];
            #pragma unroll
            for (int j = 0; j < 4; ++j) {
                float x = acc[j] + be_h[h] + bf2f(g_hs[j][h]) + bf2f(g_hr[j][h]);
                x = x > 0.f ? x : 0.01f * x;
                p[j] = x * a_h[h];
            }
            #pragma unroll
            for (int j = 0; j < 4; ++j) {
                p[j] += __shfl_xor(p[j], 1);
                p[j] += __shfl_xor(p[j], 2);
            }
            float q = (jm & 1) ? ((jm & 2) ? p[3] : p[1])
                               : ((jm & 2) ? p[2] : p[0]);
            q += __shfl_xor(q, 4);
            q += __shfl_xor(q, 8);
            float e_ = __expf(q);
            if (li < 4) {
                int pos = p0 + wv * 16 + lg * 4 + li;
                ex[(size_t)pos * HEADS + h] = e_;    // CSR-contiguous write
            }
        }
    }
}

// ---------- K3: per-node gather; s_csr/ex contiguous, hs random -------------
__global__ __launch_bounds__(256) void k_gather_out(
    const int* __restrict__ rowptr, const int* __restrict__ s_csr,
    const unsigned short* __restrict__ hsb, const float* __restrict__ ex,
    float* __restrict__ out)
{
    int r = blockIdx.x * 4 + (threadIdx.x >> 6);
    int l = threadIdx.x & 63;
    int h = l >> 3;
    int beg = rowptr[r], end = rowptr[r + 1];

    float2 acc = make_float2(0.f, 0.f);
    float dsum = 0.f;
    for (int j0 = beg; j0 < end; j0 += 8) {
        int cnt = end - j0;
        int s[8]; float w[8];
        #pragma unroll
        for (int q = 0; q < 8; ++q)
            if (q < cnt) { s[q] = s_csr[j0 + q]; w[q] = ex[(size_t)(j0 + q) * HEADS + h]; }
        #pragma unroll
        for (int q = 0; q < 8; ++q)
            if (q < cnt) {
                ushort2 hv = *(const ushort2*)&hsb[(size_t)s[q] * D + 2 * l];
                acc.x += w[q] * bf2f(hv.x);
                acc.y += w[q] * bf2f(hv.y);
                dsum  += w[q];
            }
    }
    float inv = (end > beg && dsum != 0.f) ? (1.0f / dsum) : 0.f;
    acc.x *= inv; acc.y *= inv;
    *(float2*)&out[(size_t)r * D + 2 * l] = acc;
}

extern "C" void kernel_launch(void* const* d_in, const int* in_sizes, int n_in,
                              void* d_out, int out_size, void* d_ws, size_t ws_size,
                              hipStream_t stream) {
    const float* nodes     = (const float*)d_in[0];
    const float* edges     = (const float*)d_in[1];
    const int*   senders   = (const int*)d_in[2];
    const int*   receivers = (const int*)d_in[3];
    const float* Ws = (const float*)d_in[4];
    const float* bs = (const float*)d_in[5];
    const float* Wr = (const float*)d_in[6];
    const float* br = (const float*)d_in[7];
    const float* We = (const float*)d_in[8];
    const float* be = (const float*)d_in[9];
    const float* a  = (const float*)d_in[10];
    float* out = (float*)d_out;

    unsigned short* hsb = (unsigned short*)d_ws;          // 6.4M bf16
    unsigned short* hrb = hsb + (size_t)N_NODES * D;      // 6.4M bf16
    float* ex   = (float*)(hrb + (size_t)N_NODES * D);    // 6.4M f32 (CSR order)
    int* deg    = (int*)(ex + (size_t)N_EDGES * HEADS);   // 50000
    int* rowptr = deg + N_NODES;                          // 50001
    int* cursor = rowptr + N_NODES + 1;                   // 50000
    int* eids   = cursor + N_NODES;                       // 800000
    int* s_csr  = eids + N_EDGES;                         // 800000
    int* r_csr  = s_csr + N_EDGES;                        // 800000

    // CSR build first (K2 consumes it)
    hipMemsetAsync(deg, 0, N_NODES * sizeof(int), stream);
    k_hist<<<N_EDGES / 256, 256, 0, stream>>>(receivers, deg);
    k_scan<<<1, 1024, 0, stream>>>(deg, rowptr, cursor);
    k_fill<<<N_EDGES / 256, 256, 0, stream>>>(receivers, senders, cursor,
                                              eids, s_csr, r_csr);
    int ntiles_n = (N_NODES + K1_ROWS - 1) / K1_ROWS;
    k_node_proj_mfma<<<ntiles_n * 2, 256, 0, stream>>>(nodes, Ws, bs, Wr, br, hsb, hrb);
    k_edge_logits_mfma<<<2048, 256, 0, stream>>>(edges, eids, s_csr, r_csr,
                                                 We, be, a, hsb, hrb, ex);
    k_gather_out<<<N_NODES / 4, 256, 0, stream>>>(rowptr, s_csr, hsb, ex, out);
}